// Round 1
// baseline (1131.720 us; speedup 1.0000x reference)
//
#include <hip/hip_runtime.h>
#include <hip/hip_bf16.h>

// Problem constants (fixed by the reference)
#define N_GENES_MAX 5000
#define PARAMS_PER_GENE 445
// Per-gene table layout (floats), per transform t: [locs(n), heights(n), lcdf(n), widths(n-1), pad]
// t0 (n=128): offset 0,   size 512
// t1 (n=64):  offset 512, size 256
// t2 (n=32):  offset 768, size 128
#define TABLE_STRIDE 896

// Persistent table buffer (module-static; rewritten every launch, so every call
// does identical work — no reliance on prior state, graph-capture safe).
__device__ float g_tables[(size_t)N_GENES_MAX * TABLE_STRIDE];

// ---------------------------------------------------------------------------
// Kernel 1: build per-gene spline tables.
// grid = (G, 3), block = 128. One block per (gene, transform).
// ---------------------------------------------------------------------------
__global__ void build_tables(const float* __restrict__ params) {
    const int g = blockIdx.x;
    const int t = blockIdx.y;
    const int ns[3]   = {128, 64, 32};
    const int poff[3] = {0, 255, 382};   // heights start within a gene's 445 params
    const int toff[3] = {0, 512, 768};   // table offset within gene's TABLE_STRIDE block

    const int n = ns[t];
    const int m = n - 1;                 // number of widths
    const float* ph = params + (size_t)g * PARAMS_PER_GENE + poff[t];
    const float* pw = ph + n;
    float* tab     = g_tables + (size_t)g * TABLE_STRIDE + toff[t];
    float* locs    = tab;
    float* heights = tab + n;
    float* lcdf    = tab + 2 * n;
    float* widths  = tab + 3 * n;

    __shared__ float s_scan[128];
    __shared__ float s_h[129];
    __shared__ float s_red[128];

    const int tid = threadIdx.x;

    // ---- softmax over widths ----
    float uw = (tid < m) ? pw[tid] : -1e30f;
    s_red[tid] = uw;
    __syncthreads();
    for (int s = 64; s > 0; s >>= 1) {
        if (tid < s) s_red[tid] = fmaxf(s_red[tid], s_red[tid + s]);
        __syncthreads();
    }
    const float mx = s_red[0];
    __syncthreads();
    float e = (tid < m) ? expf(uw - mx) : 0.0f;

    // inclusive scan of e (Hillis-Steele over 128 lanes; tails are zero)
    s_scan[tid] = e;
    __syncthreads();
    #pragma unroll
    for (int off = 1; off < 128; off <<= 1) {
        float v = (tid >= off) ? s_scan[tid - off] : 0.0f;
        __syncthreads();
        s_scan[tid] += v;
        __syncthreads();
    }
    const float S = s_scan[m - 1];
    const float invS = 1.0f / S;
    const float w_i = e * invS;                 // widths[tid], valid tid < m
    if (tid < m) widths[tid] = w_i;
    if (tid == 0) locs[0] = 0.0f;
    if (tid < m) locs[tid + 1] = (tid == m - 1) ? 1.0f : s_scan[tid] * invS;
    __syncthreads();

    // ---- heights ----
    float uh = (tid < n) ? ph[tid] : 0.0f;
    float eh = (tid < n) ? expf(uh) : 0.0f;
    s_h[tid] = eh;
    if (tid == 0) s_h[128] = 0.0f;
    __syncthreads();
    float term = (tid < m) ? 0.5f * (s_h[tid] + s_h[tid + 1]) * w_i : 0.0f;
    s_red[tid] = term;
    __syncthreads();
    for (int s = 64; s > 0; s >>= 1) {
        if (tid < s) s_red[tid] += s_red[tid + s];
        __syncthreads();
    }
    const float area = s_red[0];
    __syncthreads();
    const float inv_area = 1.0f / area;
    if (tid < n) heights[tid] = eh * inv_area;

    // ---- left CDF: inclusive scan of 0.5*(h[i]+h[i+1])*w[i] ----
    float d = term * inv_area;
    s_scan[tid] = d;
    __syncthreads();
    #pragma unroll
    for (int off = 1; off < 128; off <<= 1) {
        float v = (tid >= off) ? s_scan[tid - off] : 0.0f;
        __syncthreads();
        s_scan[tid] += v;
        __syncthreads();
    }
    if (tid == 0) lcdf[0] = 0.0f;
    if (tid < m) lcdf[tid + 1] = (tid == m - 1) ? 1.0f : s_scan[tid];
}

// ---------------------------------------------------------------------------
// Kernel 2: per-element spline evaluation (3 stacked transforms).
// ---------------------------------------------------------------------------
template <int K>
__device__ __forceinline__ int bin_search(const float* __restrict__ locs, float x) {
    // Exact mirror of reference: fixed ceil(log2(K+1)) iterations, clipped.
    int lo = 0, hi = K;
    constexpr int ITERS = (K == 128) ? 8 : (K == 64) ? 7 : 6;
    #pragma unroll
    for (int it = 0; it < ITERS; ++it) {
        int mid = (lo + hi) >> 1;
        mid = (mid > K - 1) ? (K - 1) : mid;
        const bool pred = locs[mid] <= x;
        lo = pred ? mid + 1 : lo;
        hi = pred ? hi : mid;
    }
    int b = lo - 1;
    b = (b < 0) ? 0 : b;
    b = (b > K - 2) ? (K - 2) : b;
    return b;
}

template <int K>
__device__ __forceinline__ void spline_step(const float* __restrict__ tab, float& x, float& lad) {
    const float* locs    = tab;
    const float* heights = tab + K;
    const float* lcdf    = tab + 2 * K;
    const float* widths  = tab + 3 * K;
    const int b = bin_search<K>(locs, x);
    const float bl = locs[b];
    const float w  = widths[b];
    const float lh = heights[b];
    const float rh = heights[b + 1];
    const float lc = lcdf[b];
    const float alpha = (x - bl) / w;
    float out = (0.5f * (rh - lh) * w) * alpha * alpha + (lh * w) * alpha + lc;
    out = fminf(fmaxf(out, 0.0f), 1.0f);
    lad += __logf(alpha * (rh - lh) + lh);
    x = out;
}

__global__ void spline_eval(const float* __restrict__ x_in,
                            const int* __restrict__ gix,
                            float* __restrict__ out, int N) {
    const int i = blockIdx.x * blockDim.x + threadIdx.x;
    if (i >= N) return;
    float x = x_in[i];
    const float* tab = g_tables + (size_t)gix[i] * TABLE_STRIDE;
    float lad = 0.0f;
    spline_step<128>(tab, x, lad);
    spline_step<64>(tab + 512, x, lad);
    spline_step<32>(tab + 768, x, lad);
    out[i] = x;
    out[N + i] = lad;
}

// ---------------------------------------------------------------------------
extern "C" void kernel_launch(void* const* d_in, const int* in_sizes, int n_in,
                              void* d_out, int out_size, void* d_ws, size_t ws_size,
                              hipStream_t stream) {
    const float* x      = (const float*)d_in[0];
    const int*   gix    = (const int*)d_in[1];
    const float* params = (const float*)d_in[2];
    float* out = (float*)d_out;

    const int N = in_sizes[0];
    const int G = in_sizes[2] / PARAMS_PER_GENE;

    build_tables<<<dim3(G, 3), 128, 0, stream>>>(params);
    const int block = 256;
    const int grid = (N + block - 1) / block;
    spline_eval<<<grid, block, 0, stream>>>(x, gix, out, N);
}

// Round 2
// 661.111 us; speedup vs baseline: 1.7118x; 1.7118x over previous
//
#include <hip/hip_runtime.h>
#include <hip/hip_bf16.h>

// Problem constants (fixed by the reference)
#define N_GENES_MAX 5000
#define N_ELEM_MAX  4000000
#define PARAMS_PER_GENE 445
// Per-gene table layout (floats), per transform t: [locs(n), heights(n), lcdf(n), widths(n-1), pad]
// t0 (n=128): offset 0,   size 512
// t1 (n=64):  offset 512, size 256
// t2 (n=32):  offset 768, size 128
#define TABLE_STRIDE 896

// Persistent buffers (module-static; fully rewritten every launch — no
// reliance on prior state, graph-capture safe).
__device__ float g_tables[(size_t)N_GENES_MAX * TABLE_STRIDE];
__device__ float g_sx[N_ELEM_MAX];    // x values sorted by gene
__device__ int   g_sidx[N_ELEM_MAX];  // original element index, sorted by gene

// ---------------------------------------------------------------------------
// Kernel 1: build per-gene spline tables. grid=(G,3), block=128.
// ---------------------------------------------------------------------------
__global__ void build_tables(const float* __restrict__ params) {
    const int g = blockIdx.x;
    const int t = blockIdx.y;
    const int ns[3]   = {128, 64, 32};
    const int poff[3] = {0, 255, 382};
    const int toff[3] = {0, 512, 768};

    const int n = ns[t];
    const int m = n - 1;
    const float* ph = params + (size_t)g * PARAMS_PER_GENE + poff[t];
    const float* pw = ph + n;
    float* tab     = g_tables + (size_t)g * TABLE_STRIDE + toff[t];
    float* locs    = tab;
    float* heights = tab + n;
    float* lcdf    = tab + 2 * n;
    float* widths  = tab + 3 * n;

    __shared__ float s_scan[128];
    __shared__ float s_h[129];
    __shared__ float s_red[128];

    const int tid = threadIdx.x;

    // ---- softmax over widths ----
    float uw = (tid < m) ? pw[tid] : -1e30f;
    s_red[tid] = uw;
    __syncthreads();
    for (int s = 64; s > 0; s >>= 1) {
        if (tid < s) s_red[tid] = fmaxf(s_red[tid], s_red[tid + s]);
        __syncthreads();
    }
    const float mx = s_red[0];
    __syncthreads();
    float e = (tid < m) ? expf(uw - mx) : 0.0f;

    s_scan[tid] = e;
    __syncthreads();
    #pragma unroll
    for (int off = 1; off < 128; off <<= 1) {
        float v = (tid >= off) ? s_scan[tid - off] : 0.0f;
        __syncthreads();
        s_scan[tid] += v;
        __syncthreads();
    }
    const float S = s_scan[m - 1];
    const float invS = 1.0f / S;
    const float w_i = e * invS;
    if (tid < m) widths[tid] = w_i;
    if (tid == 0) locs[0] = 0.0f;
    if (tid < m) locs[tid + 1] = (tid == m - 1) ? 1.0f : s_scan[tid] * invS;
    __syncthreads();

    // ---- heights ----
    float uh = (tid < n) ? ph[tid] : 0.0f;
    float eh = (tid < n) ? expf(uh) : 0.0f;
    s_h[tid] = eh;
    if (tid == 0) s_h[128] = 0.0f;
    __syncthreads();
    float term = (tid < m) ? 0.5f * (s_h[tid] + s_h[tid + 1]) * w_i : 0.0f;
    s_red[tid] = term;
    __syncthreads();
    for (int s = 64; s > 0; s >>= 1) {
        if (tid < s) s_red[tid] += s_red[tid + s];
        __syncthreads();
    }
    const float area = s_red[0];
    __syncthreads();
    const float inv_area = 1.0f / area;
    if (tid < n) heights[tid] = eh * inv_area;

    float d = term * inv_area;
    s_scan[tid] = d;
    __syncthreads();
    #pragma unroll
    for (int off = 1; off < 128; off <<= 1) {
        float v = (tid >= off) ? s_scan[tid - off] : 0.0f;
        __syncthreads();
        s_scan[tid] += v;
        __syncthreads();
    }
    if (tid == 0) lcdf[0] = 0.0f;
    if (tid < m) lcdf[tid + 1] = (tid == m - 1) ? 1.0f : s_scan[tid];
}

// ---------------------------------------------------------------------------
// Counting sort by gene: histogram -> scan -> scatter.
// d_ws layout (ints): counts[G], offs[G+1], cursor[G]
// ---------------------------------------------------------------------------
__global__ void hist_kernel(const int* __restrict__ gix, int* __restrict__ counts, int N) {
    const int i = blockIdx.x * blockDim.x + threadIdx.x;
    if (i < N) atomicAdd(&counts[gix[i]], 1);
}

__global__ void scan_counts(const int* __restrict__ counts, int* __restrict__ offs,
                            int* __restrict__ cursor, int G) {
    __shared__ int s_part[1024];
    const int tid = threadIdx.x;
    const int CH = (G + 1023) / 1024;  // elements per thread (<=8)
    int local[8];
    int sum = 0;
    for (int k = 0; k < CH; ++k) {
        const int idx = tid * CH + k;
        const int v = (idx < G) ? counts[idx] : 0;
        local[k] = sum;   // exclusive within this thread's chunk
        sum += v;
    }
    s_part[tid] = sum;
    __syncthreads();
    for (int off = 1; off < 1024; off <<= 1) {
        int v = (tid >= off) ? s_part[tid - off] : 0;
        __syncthreads();
        s_part[tid] += v;
        __syncthreads();
    }
    const int prev = (tid == 0) ? 0 : s_part[tid - 1];
    for (int k = 0; k < CH; ++k) {
        const int idx = tid * CH + k;
        if (idx < G) {
            const int o = prev + local[k];
            offs[idx] = o;
            cursor[idx] = o;
        }
    }
    if (tid == 1023) offs[G] = s_part[1023];
}

__global__ void scatter_kernel(const float* __restrict__ x, const int* __restrict__ gix,
                               int* __restrict__ cursor, int N) {
    const int i = blockIdx.x * blockDim.x + threadIdx.x;
    if (i >= N) return;
    const int g = gix[i];
    const int pos = atomicAdd(&cursor[g], 1);
    g_sx[pos] = x[i];
    g_sidx[pos] = i;
}

// ---------------------------------------------------------------------------
// Kernel 5: per-gene evaluation with LDS-staged table.
// ---------------------------------------------------------------------------
template <int K>
__device__ __forceinline__ void spline_step_lds(const float* __restrict__ tab,
                                                float& x, float& lad) {
    const float* locs    = tab;
    const float* heights = tab + K;
    const float* lcdf    = tab + 2 * K;
    const float* widths  = tab + 3 * K;

    // Near-uniform bins: guess + local scan. Result equals
    // clip(searchsorted(locs, x, 'right') - 1, 0, K-2).
    int b = (int)(x * (float)(K - 1));
    b = (b < 0) ? 0 : ((b > K - 2) ? K - 2 : b);
    while (b > 0 && locs[b] > x) --b;
    while (b < K - 2 && locs[b + 1] <= x) ++b;

    const float bl = locs[b];
    const float w  = widths[b];
    const float lh = heights[b];
    const float rh = heights[b + 1];
    const float lc = lcdf[b];
    const float alpha = (x - bl) / w;
    float out = (0.5f * (rh - lh) * w) * alpha * alpha + (lh * w) * alpha + lc;
    out = fminf(fmaxf(out, 0.0f), 1.0f);
    lad += __logf(alpha * (rh - lh) + lh);
    x = out;
}

__global__ void spline_eval_sorted(const int* __restrict__ offs,
                                   float* __restrict__ out, int N) {
    const int g = blockIdx.x;
    __shared__ float s_tab[TABLE_STRIDE];
    const float* tab = g_tables + (size_t)g * TABLE_STRIDE;
    for (int i = threadIdx.x; i < TABLE_STRIDE; i += blockDim.x) s_tab[i] = tab[i];
    __syncthreads();

    const int start = offs[g];
    const int end   = offs[g + 1];
    for (int j = start + threadIdx.x; j < end; j += blockDim.x) {
        float x = g_sx[j];
        float lad = 0.0f;
        spline_step_lds<128>(s_tab, x, lad);
        spline_step_lds<64>(s_tab + 512, x, lad);
        spline_step_lds<32>(s_tab + 768, x, lad);
        const int o = g_sidx[j];
        out[o] = x;
        out[N + o] = lad;
    }
}

// ---------------------------------------------------------------------------
extern "C" void kernel_launch(void* const* d_in, const int* in_sizes, int n_in,
                              void* d_out, int out_size, void* d_ws, size_t ws_size,
                              hipStream_t stream) {
    const float* x      = (const float*)d_in[0];
    const int*   gix    = (const int*)d_in[1];
    const float* params = (const float*)d_in[2];
    float* out = (float*)d_out;

    const int N = in_sizes[0];
    const int G = in_sizes[2] / PARAMS_PER_GENE;

    int* counts = (int*)d_ws;           // [G]
    int* offs   = counts + G;           // [G+1]
    int* cursor = offs + G + 1;         // [G]

    hipMemsetAsync(counts, 0, (size_t)G * sizeof(int), stream);

    build_tables<<<dim3(G, 3), 128, 0, stream>>>(params);

    const int block = 256;
    const int grid = (N + block - 1) / block;
    hist_kernel<<<grid, block, 0, stream>>>(gix, counts, N);
    scan_counts<<<1, 1024, 0, stream>>>(counts, offs, cursor, G);
    scatter_kernel<<<grid, block, 0, stream>>>(x, gix, cursor, N);
    spline_eval_sorted<<<G, block, 0, stream>>>(offs, out, N);
}

// Round 3
// 624.918 us; speedup vs baseline: 1.8110x; 1.0579x over previous
//
#include <hip/hip_runtime.h>
#include <hip/hip_bf16.h>

// Problem constants (fixed by the reference)
#define N_GENES_MAX 5000
#define N_ELEM_MAX  4000000
#define PARAMS_PER_GENE 445
// Per-gene table layout (floats), per transform t: [locs(n), heights(n), lcdf(n), widths(n-1), pad]
// t0 (n=128): offset 0,   size 512
// t1 (n=64):  offset 512, size 256
// t2 (n=32):  offset 768, size 128
#define TABLE_STRIDE 896

// Persistent buffers (module-static; fully rewritten every launch — no
// reliance on prior state, graph-capture safe).
__device__ float  g_tables[(size_t)N_GENES_MAX * TABLE_STRIDE];
__device__ float  g_sx[N_ELEM_MAX];     // x values sorted by gene
__device__ int    g_rank[N_ELEM_MAX];   // i -> sorted position (coalesced by i)
__device__ float2 g_res[N_ELEM_MAX];    // {out, lad} in sorted order

// ---------------------------------------------------------------------------
// Kernel 1: build per-gene spline tables. grid=(G,3), block=128.
// ---------------------------------------------------------------------------
__global__ void build_tables(const float* __restrict__ params) {
    const int g = blockIdx.x;
    const int t = blockIdx.y;
    const int ns[3]   = {128, 64, 32};
    const int poff[3] = {0, 255, 382};
    const int toff[3] = {0, 512, 768};

    const int n = ns[t];
    const int m = n - 1;
    const float* ph = params + (size_t)g * PARAMS_PER_GENE + poff[t];
    const float* pw = ph + n;
    float* tab     = g_tables + (size_t)g * TABLE_STRIDE + toff[t];
    float* locs    = tab;
    float* heights = tab + n;
    float* lcdf    = tab + 2 * n;
    float* widths  = tab + 3 * n;

    __shared__ float s_scan[128];
    __shared__ float s_h[129];
    __shared__ float s_red[128];

    const int tid = threadIdx.x;

    // ---- softmax over widths ----
    float uw = (tid < m) ? pw[tid] : -1e30f;
    s_red[tid] = uw;
    __syncthreads();
    for (int s = 64; s > 0; s >>= 1) {
        if (tid < s) s_red[tid] = fmaxf(s_red[tid], s_red[tid + s]);
        __syncthreads();
    }
    const float mx = s_red[0];
    __syncthreads();
    float e = (tid < m) ? expf(uw - mx) : 0.0f;

    s_scan[tid] = e;
    __syncthreads();
    #pragma unroll
    for (int off = 1; off < 128; off <<= 1) {
        float v = (tid >= off) ? s_scan[tid - off] : 0.0f;
        __syncthreads();
        s_scan[tid] += v;
        __syncthreads();
    }
    const float S = s_scan[m - 1];
    const float invS = 1.0f / S;
    const float w_i = e * invS;
    if (tid < m) widths[tid] = w_i;
    if (tid == 0) locs[0] = 0.0f;
    if (tid < m) locs[tid + 1] = (tid == m - 1) ? 1.0f : s_scan[tid] * invS;
    __syncthreads();

    // ---- heights ----
    float uh = (tid < n) ? ph[tid] : 0.0f;
    float eh = (tid < n) ? expf(uh) : 0.0f;
    s_h[tid] = eh;
    if (tid == 0) s_h[128] = 0.0f;
    __syncthreads();
    float term = (tid < m) ? 0.5f * (s_h[tid] + s_h[tid + 1]) * w_i : 0.0f;
    s_red[tid] = term;
    __syncthreads();
    for (int s = 64; s > 0; s >>= 1) {
        if (tid < s) s_red[tid] += s_red[tid + s];
        __syncthreads();
    }
    const float area = s_red[0];
    __syncthreads();
    const float inv_area = 1.0f / area;
    if (tid < n) heights[tid] = eh * inv_area;

    float d = term * inv_area;
    s_scan[tid] = d;
    __syncthreads();
    #pragma unroll
    for (int off = 1; off < 128; off <<= 1) {
        float v = (tid >= off) ? s_scan[tid - off] : 0.0f;
        __syncthreads();
        s_scan[tid] += v;
        __syncthreads();
    }
    if (tid == 0) lcdf[0] = 0.0f;
    if (tid < m) lcdf[tid + 1] = (tid == m - 1) ? 1.0f : s_scan[tid];
}

// ---------------------------------------------------------------------------
// Counting sort by gene: histogram -> scan -> scatter(rank).
// d_ws layout (ints): counts[G], offs[G+1], cursor[G]
// ---------------------------------------------------------------------------
__global__ void hist_kernel(const int* __restrict__ gix, int* __restrict__ counts, int N) {
    const int i = blockIdx.x * blockDim.x + threadIdx.x;
    const int i4 = i * 4;
    if (i4 + 3 < N) {
        const int4 g4 = *(const int4*)(gix + i4);
        atomicAdd(&counts[g4.x], 1);
        atomicAdd(&counts[g4.y], 1);
        atomicAdd(&counts[g4.z], 1);
        atomicAdd(&counts[g4.w], 1);
    } else {
        for (int k = i4; k < N; ++k) atomicAdd(&counts[gix[k]], 1);
    }
}

__global__ void scan_counts(const int* __restrict__ counts, int* __restrict__ offs,
                            int* __restrict__ cursor, int G) {
    __shared__ int s_part[1024];
    const int tid = threadIdx.x;
    const int CH = (G + 1023) / 1024;  // elements per thread (<=8)
    int local[8];
    int sum = 0;
    for (int k = 0; k < CH; ++k) {
        const int idx = tid * CH + k;
        const int v = (idx < G) ? counts[idx] : 0;
        local[k] = sum;
        sum += v;
    }
    s_part[tid] = sum;
    __syncthreads();
    for (int off = 1; off < 1024; off <<= 1) {
        int v = (tid >= off) ? s_part[tid - off] : 0;
        __syncthreads();
        s_part[tid] += v;
        __syncthreads();
    }
    const int prev = (tid == 0) ? 0 : s_part[tid - 1];
    for (int k = 0; k < CH; ++k) {
        const int idx = tid * CH + k;
        if (idx < G) {
            const int o = prev + local[k];
            offs[idx] = o;
            cursor[idx] = o;
        }
    }
    if (tid == 1023) offs[G] = s_part[1023];
}

// One random 4B line per element (g_sx[pos]); rank write is coalesced.
__global__ void scatter_kernel(const float* __restrict__ x, const int* __restrict__ gix,
                               int* __restrict__ cursor, int N) {
    const int i = blockIdx.x * blockDim.x + threadIdx.x;
    if (i >= N) return;
    const int g = gix[i];
    const int pos = atomicAdd(&cursor[g], 1);
    g_sx[pos] = x[i];
    g_rank[i] = pos;
}

// ---------------------------------------------------------------------------
// Kernel 5: per-gene evaluation with LDS-staged table; coalesced output.
// ---------------------------------------------------------------------------
template <int K>
__device__ __forceinline__ void spline_step_lds(const float* __restrict__ tab,
                                                float& x, float& lad) {
    const float* locs    = tab;
    const float* heights = tab + K;
    const float* lcdf    = tab + 2 * K;
    const float* widths  = tab + 3 * K;

    // Near-uniform bins: guess + local scan. Result equals
    // clip(searchsorted(locs, x, 'right') - 1, 0, K-2).
    int b = (int)(x * (float)(K - 1));
    b = (b < 0) ? 0 : ((b > K - 2) ? K - 2 : b);
    while (b > 0 && locs[b] > x) --b;
    while (b < K - 2 && locs[b + 1] <= x) ++b;

    const float bl = locs[b];
    const float w  = widths[b];
    const float lh = heights[b];
    const float rh = heights[b + 1];
    const float lc = lcdf[b];
    const float alpha = (x - bl) / w;
    float out = (0.5f * (rh - lh) * w) * alpha * alpha + (lh * w) * alpha + lc;
    out = fminf(fmaxf(out, 0.0f), 1.0f);
    lad += __logf(alpha * (rh - lh) + lh);
    x = out;
}

__global__ void spline_eval_sorted(const int* __restrict__ offs) {
    const int g = blockIdx.x;
    __shared__ float s_tab[TABLE_STRIDE];
    const float* tab = g_tables + (size_t)g * TABLE_STRIDE;
    for (int i = threadIdx.x; i < TABLE_STRIDE; i += blockDim.x) s_tab[i] = tab[i];
    __syncthreads();

    const int start = offs[g];
    const int end   = offs[g + 1];
    for (int j = start + threadIdx.x; j < end; j += blockDim.x) {
        float x = g_sx[j];
        float lad = 0.0f;
        spline_step_lds<128>(s_tab, x, lad);
        spline_step_lds<64>(s_tab + 512, x, lad);
        spline_step_lds<32>(s_tab + 768, x, lad);
        g_res[j] = make_float2(x, lad);   // coalesced
    }
}

// ---------------------------------------------------------------------------
// Kernel 6: unpermute — one random 8B gather per element, coalesced writes.
// ---------------------------------------------------------------------------
__global__ void unpermute(float* __restrict__ out, int N) {
    const int i = blockIdx.x * blockDim.x + threadIdx.x;
    if (i >= N) return;
    const int r = g_rank[i];
    const float2 v = g_res[r];
    out[i] = v.x;
    out[N + i] = v.y;
}

// ---------------------------------------------------------------------------
extern "C" void kernel_launch(void* const* d_in, const int* in_sizes, int n_in,
                              void* d_out, int out_size, void* d_ws, size_t ws_size,
                              hipStream_t stream) {
    const float* x      = (const float*)d_in[0];
    const int*   gix    = (const int*)d_in[1];
    const float* params = (const float*)d_in[2];
    float* out = (float*)d_out;

    const int N = in_sizes[0];
    const int G = in_sizes[2] / PARAMS_PER_GENE;

    int* counts = (int*)d_ws;           // [G]
    int* offs   = counts + G;           // [G+1]
    int* cursor = offs + G + 1;         // [G]

    hipMemsetAsync(counts, 0, (size_t)G * sizeof(int), stream);

    build_tables<<<dim3(G, 3), 128, 0, stream>>>(params);

    const int block = 256;
    const int grid = (N + block - 1) / block;
    const int grid4 = (N / 4 + block - 1) / block;
    hist_kernel<<<grid4, block, 0, stream>>>(gix, counts, N);
    scan_counts<<<1, 1024, 0, stream>>>(counts, offs, cursor, G);
    scatter_kernel<<<grid, block, 0, stream>>>(x, gix, cursor, N);
    spline_eval_sorted<<<G, block, 0, stream>>>(offs);
    unpermute<<<grid, block, 0, stream>>>(out, N);
}

// Round 4
// 437.451 us; speedup vs baseline: 2.5871x; 1.4285x over previous
//
#include <hip/hip_runtime.h>
#include <hip/hip_bf16.h>

// Problem constants (fixed by the reference)
#define N_GENES_MAX 5000
#define N_ELEM_MAX  4000000
#define PARAMS_PER_GENE 445
// Per-gene table layout (floats), per transform t: [locs(n), heights(n), lcdf(n), widths(n-1), pad]
#define TABLE_STRIDE 896

// Tile-based counting sort
#define TILE 8192
#define MAX_NB 512           // TILE*MAX_NB = 4,194,304 >= N_ELEM_MAX

// Persistent buffers (module-static; fully rewritten every launch — no
// reliance on prior state, graph-capture safe).
__device__ float  g_tables[(size_t)N_GENES_MAX * TABLE_STRIDE];
__device__ float  g_sx[N_ELEM_MAX];     // x values sorted by gene
__device__ int    g_rank[N_ELEM_MAX];   // i -> sorted position (coalesced by i)
__device__ float2 g_res[N_ELEM_MAX];    // {out, lad} in sorted order
__device__ int    g_counts[(size_t)MAX_NB * N_GENES_MAX];  // per-(tile,gene) counts
__device__ int    g_offsm[(size_t)MAX_NB * N_GENES_MAX];   // per-(tile,gene) start offsets

// ---------------------------------------------------------------------------
// Kernel 1: build per-gene spline tables. grid=(G,3), block=128.
// ---------------------------------------------------------------------------
__global__ void build_tables(const float* __restrict__ params) {
    const int g = blockIdx.x;
    const int t = blockIdx.y;
    const int ns[3]   = {128, 64, 32};
    const int poff[3] = {0, 255, 382};
    const int toff[3] = {0, 512, 768};

    const int n = ns[t];
    const int m = n - 1;
    const float* ph = params + (size_t)g * PARAMS_PER_GENE + poff[t];
    const float* pw = ph + n;
    float* tab     = g_tables + (size_t)g * TABLE_STRIDE + toff[t];
    float* locs    = tab;
    float* heights = tab + n;
    float* lcdf    = tab + 2 * n;
    float* widths  = tab + 3 * n;

    __shared__ float s_scan[128];
    __shared__ float s_h[129];
    __shared__ float s_red[128];

    const int tid = threadIdx.x;

    // ---- softmax over widths ----
    float uw = (tid < m) ? pw[tid] : -1e30f;
    s_red[tid] = uw;
    __syncthreads();
    for (int s = 64; s > 0; s >>= 1) {
        if (tid < s) s_red[tid] = fmaxf(s_red[tid], s_red[tid + s]);
        __syncthreads();
    }
    const float mx = s_red[0];
    __syncthreads();
    float e = (tid < m) ? expf(uw - mx) : 0.0f;

    s_scan[tid] = e;
    __syncthreads();
    #pragma unroll
    for (int off = 1; off < 128; off <<= 1) {
        float v = (tid >= off) ? s_scan[tid - off] : 0.0f;
        __syncthreads();
        s_scan[tid] += v;
        __syncthreads();
    }
    const float S = s_scan[m - 1];
    const float invS = 1.0f / S;
    const float w_i = e * invS;
    if (tid < m) widths[tid] = w_i;
    if (tid == 0) locs[0] = 0.0f;
    if (tid < m) locs[tid + 1] = (tid == m - 1) ? 1.0f : s_scan[tid] * invS;
    __syncthreads();

    // ---- heights ----
    float uh = (tid < n) ? ph[tid] : 0.0f;
    float eh = (tid < n) ? expf(uh) : 0.0f;
    s_h[tid] = eh;
    if (tid == 0) s_h[128] = 0.0f;
    __syncthreads();
    float term = (tid < m) ? 0.5f * (s_h[tid] + s_h[tid + 1]) * w_i : 0.0f;
    s_red[tid] = term;
    __syncthreads();
    for (int s = 64; s > 0; s >>= 1) {
        if (tid < s) s_red[tid] += s_red[tid + s];
        __syncthreads();
    }
    const float area = s_red[0];
    __syncthreads();
    const float inv_area = 1.0f / area;
    if (tid < n) heights[tid] = eh * inv_area;

    float d = term * inv_area;
    s_scan[tid] = d;
    __syncthreads();
    #pragma unroll
    for (int off = 1; off < 128; off <<= 1) {
        float v = (tid >= off) ? s_scan[tid - off] : 0.0f;
        __syncthreads();
        s_scan[tid] += v;
        __syncthreads();
    }
    if (tid == 0) lcdf[0] = 0.0f;
    if (tid < m) lcdf[tid + 1] = (tid == m - 1) ? 1.0f : s_scan[tid];
}

// ---------------------------------------------------------------------------
// Kernel 2: per-tile LDS histogram (no global atomics).
// ---------------------------------------------------------------------------
__global__ void blockhist(const int* __restrict__ gix, int N, int G) {
    __shared__ int h[N_GENES_MAX];
    const int b = blockIdx.x;
    const int tid = threadIdx.x;
    for (int g = tid; g < G; g += blockDim.x) h[g] = 0;
    __syncthreads();

    const int base = b * TILE;
    const int n4 = TILE / 4;
    const int4* gix4 = (const int4*)gix + (base >> 2);
    for (int k = tid; k < n4; k += blockDim.x) {
        const int gi = base + 4 * k;
        if (gi + 3 < N) {
            const int4 v = gix4[k];
            atomicAdd(&h[v.x], 1);
            atomicAdd(&h[v.y], 1);
            atomicAdd(&h[v.z], 1);
            atomicAdd(&h[v.w], 1);
        } else {
            for (int c = 0; c < 4; ++c)
                if (gi + c < N) atomicAdd(&h[gix[gi + c]], 1);
        }
    }
    __syncthreads();
    for (int g = tid; g < G; g += blockDim.x) g_counts[(size_t)b * G + g] = h[g];
}

// ---------------------------------------------------------------------------
// Kernel 3: per-gene totals (coalesced column reduction).
// ---------------------------------------------------------------------------
__global__ void reduce_genes(int* __restrict__ geneTotal, int G, int NB) {
    const int g = blockIdx.x * blockDim.x + threadIdx.x;
    if (g >= G) return;
    int s = 0;
    for (int b = 0; b < NB; ++b) s += g_counts[(size_t)b * G + g];
    geneTotal[g] = s;
}

// ---------------------------------------------------------------------------
// Kernel 4: exclusive scan of gene totals -> offs[G+1]. Single block.
// ---------------------------------------------------------------------------
__global__ void scan_genes(const int* __restrict__ geneTotal, int* __restrict__ offs,
                           int G, int N) {
    __shared__ int s_part[1024];
    const int tid = threadIdx.x;
    const int CH = (G + 1023) / 1024;  // <=8
    int local[8];
    int sum = 0;
    for (int k = 0; k < CH; ++k) {
        const int idx = tid * CH + k;
        const int v = (idx < G) ? geneTotal[idx] : 0;
        local[k] = sum;
        sum += v;
    }
    s_part[tid] = sum;
    __syncthreads();
    for (int off = 1; off < 1024; off <<= 1) {
        int v = (tid >= off) ? s_part[tid - off] : 0;
        __syncthreads();
        s_part[tid] += v;
        __syncthreads();
    }
    const int prev = (tid == 0) ? 0 : s_part[tid - 1];
    for (int k = 0; k < CH; ++k) {
        const int idx = tid * CH + k;
        if (idx < G) offs[idx] = prev + local[k];
    }
    if (tid == 0) offs[G] = N;
}

// ---------------------------------------------------------------------------
// Kernel 5: per-(tile,gene) start offsets (coalesced column scan).
// ---------------------------------------------------------------------------
__global__ void tile_offsets(const int* __restrict__ offs, int G, int NB) {
    const int g = blockIdx.x * blockDim.x + threadIdx.x;
    if (g >= G) return;
    int run = offs[g];
    for (int b = 0; b < NB; ++b) {
        const size_t idx = (size_t)b * G + g;
        g_offsm[idx] = run;
        run += g_counts[idx];
    }
}

// ---------------------------------------------------------------------------
// Kernel 6: scatter with LDS cursors (no global atomics).
// ---------------------------------------------------------------------------
__global__ void scatter2(const float* __restrict__ x, const int* __restrict__ gix,
                         int N, int G) {
    __shared__ int cur[N_GENES_MAX];
    const int b = blockIdx.x;
    const int tid = threadIdx.x;
    for (int g = tid; g < G; g += blockDim.x) cur[g] = g_offsm[(size_t)b * G + g];
    __syncthreads();

    const int base = b * TILE;
    const int n4 = TILE / 4;
    const int4*   gix4 = (const int4*)gix + (base >> 2);
    const float4* x4p  = (const float4*)x + (base >> 2);
    int4* rank4 = (int4*)g_rank + (base >> 2);
    for (int k = tid; k < n4; k += blockDim.x) {
        const int gi = base + 4 * k;
        if (gi + 3 < N) {
            const int4   g4 = gix4[k];
            const float4 v4 = x4p[k];
            const int p0 = atomicAdd(&cur[g4.x], 1);
            const int p1 = atomicAdd(&cur[g4.y], 1);
            const int p2 = atomicAdd(&cur[g4.z], 1);
            const int p3 = atomicAdd(&cur[g4.w], 1);
            g_sx[p0] = v4.x;
            g_sx[p1] = v4.y;
            g_sx[p2] = v4.z;
            g_sx[p3] = v4.w;
            rank4[k] = make_int4(p0, p1, p2, p3);
        } else {
            for (int c = 0; c < 4; ++c) {
                if (gi + c < N) {
                    const int pos = atomicAdd(&cur[gix[gi + c]], 1);
                    g_sx[pos] = x[gi + c];
                    g_rank[gi + c] = pos;
                }
            }
        }
    }
}

// ---------------------------------------------------------------------------
// Kernel 7: per-gene evaluation with LDS-staged table; coalesced output.
// ---------------------------------------------------------------------------
template <int K>
__device__ __forceinline__ void spline_step_lds(const float* __restrict__ tab,
                                                float& x, float& lad) {
    const float* locs    = tab;
    const float* heights = tab + K;
    const float* lcdf    = tab + 2 * K;
    const float* widths  = tab + 3 * K;

    // Near-uniform bins: guess + local scan. Result equals
    // clip(searchsorted(locs, x, 'right') - 1, 0, K-2).
    int b = (int)(x * (float)(K - 1));
    b = (b < 0) ? 0 : ((b > K - 2) ? K - 2 : b);
    while (b > 0 && locs[b] > x) --b;
    while (b < K - 2 && locs[b + 1] <= x) ++b;

    const float bl = locs[b];
    const float w  = widths[b];
    const float lh = heights[b];
    const float rh = heights[b + 1];
    const float lc = lcdf[b];
    const float alpha = (x - bl) / w;
    float out = (0.5f * (rh - lh) * w) * alpha * alpha + (lh * w) * alpha + lc;
    out = fminf(fmaxf(out, 0.0f), 1.0f);
    lad += __logf(alpha * (rh - lh) + lh);
    x = out;
}

__global__ void spline_eval_sorted(const int* __restrict__ offs) {
    const int g = blockIdx.x;
    __shared__ float s_tab[TABLE_STRIDE];
    const float* tab = g_tables + (size_t)g * TABLE_STRIDE;
    for (int i = threadIdx.x; i < TABLE_STRIDE; i += blockDim.x) s_tab[i] = tab[i];
    __syncthreads();

    const int start = offs[g];
    const int end   = offs[g + 1];
    for (int j = start + threadIdx.x; j < end; j += blockDim.x) {
        float x = g_sx[j];
        float lad = 0.0f;
        spline_step_lds<128>(s_tab, x, lad);
        spline_step_lds<64>(s_tab + 512, x, lad);
        spline_step_lds<32>(s_tab + 768, x, lad);
        g_res[j] = make_float2(x, lad);   // coalesced
    }
}

// ---------------------------------------------------------------------------
// Kernel 8: unpermute — one random 8B gather per element, coalesced writes.
// ---------------------------------------------------------------------------
__global__ void unpermute(float* __restrict__ out, int N) {
    const int i = blockIdx.x * blockDim.x + threadIdx.x;
    if (i >= N) return;
    const int r = g_rank[i];
    const float2 v = g_res[r];
    out[i] = v.x;
    out[N + i] = v.y;
}

// ---------------------------------------------------------------------------
extern "C" void kernel_launch(void* const* d_in, const int* in_sizes, int n_in,
                              void* d_out, int out_size, void* d_ws, size_t ws_size,
                              hipStream_t stream) {
    const float* x      = (const float*)d_in[0];
    const int*   gix    = (const int*)d_in[1];
    const float* params = (const float*)d_in[2];
    float* out = (float*)d_out;

    const int N = in_sizes[0];
    const int G = in_sizes[2] / PARAMS_PER_GENE;
    const int NB = (N + TILE - 1) / TILE;

    int* geneTotal = (int*)d_ws;        // [G]
    int* offs      = geneTotal + G;     // [G+1]

    build_tables<<<dim3(G, 3), 128, 0, stream>>>(params);

    const int block = 256;
    blockhist<<<NB, block, 0, stream>>>(gix, N, G);
    reduce_genes<<<(G + block - 1) / block, block, 0, stream>>>(geneTotal, G, NB);
    scan_genes<<<1, 1024, 0, stream>>>(geneTotal, offs, G, N);
    tile_offsets<<<(G + block - 1) / block, block, 0, stream>>>(offs, G, NB);
    scatter2<<<NB, block, 0, stream>>>(x, gix, N, G);
    spline_eval_sorted<<<G, block, 0, stream>>>(offs);
    unpermute<<<(N + block - 1) / block, block, 0, stream>>>(out, N);
}

// Round 5
// 302.390 us; speedup vs baseline: 3.7426x; 1.4466x over previous
//
#include <hip/hip_runtime.h>
#include <hip/hip_bf16.h>

// Problem constants (fixed by the reference)
#define N_GENES_MAX 5000
#define N_ELEM_MAX  4000000
#define PARAMS_PER_GENE 445
// Per-gene table layout (floats), per transform t: [locs(n), heights(n), lcdf(n), widths(n-1), pad]
#define TABLE_STRIDE 896

// Tile-based counting sort
#define TILE 8192
#define MAX_NB 512           // TILE*MAX_NB = 4,194,304 >= N_ELEM_MAX
#define NCH 32               // chunks over the tile dimension

// Persistent buffers (module-static; fully rewritten every launch — no
// reliance on prior state, graph-capture safe).
__device__ float  g_tables[(size_t)N_GENES_MAX * TABLE_STRIDE];
__device__ float  g_sx[N_ELEM_MAX];     // x values sorted by gene
__device__ int    g_rank[N_ELEM_MAX];   // i -> sorted position (coalesced by i)
__device__ float2 g_res[N_ELEM_MAX];    // {out, lad} in sorted order
__device__ int    g_counts[(size_t)MAX_NB * N_GENES_MAX];  // per-(tile,gene) counts
__device__ int    g_offsm[(size_t)MAX_NB * N_GENES_MAX];   // per-(tile,gene) start offsets
__device__ int    g_part[(size_t)NCH * N_GENES_MAX];       // per-(chunk,gene) partial sums
__device__ int    g_chunkoff[(size_t)NCH * N_GENES_MAX];   // per-(chunk,gene) base offsets

// ---------------------------------------------------------------------------
// Kernel 1: build per-gene spline tables. grid=(G,3), block=128.
// ---------------------------------------------------------------------------
__global__ void build_tables(const float* __restrict__ params) {
    const int g = blockIdx.x;
    const int t = blockIdx.y;
    const int ns[3]   = {128, 64, 32};
    const int poff[3] = {0, 255, 382};
    const int toff[3] = {0, 512, 768};

    const int n = ns[t];
    const int m = n - 1;
    const float* ph = params + (size_t)g * PARAMS_PER_GENE + poff[t];
    const float* pw = ph + n;
    float* tab     = g_tables + (size_t)g * TABLE_STRIDE + toff[t];
    float* locs    = tab;
    float* heights = tab + n;
    float* lcdf    = tab + 2 * n;
    float* widths  = tab + 3 * n;

    __shared__ float s_scan[128];
    __shared__ float s_h[129];
    __shared__ float s_red[128];

    const int tid = threadIdx.x;

    // ---- softmax over widths ----
    float uw = (tid < m) ? pw[tid] : -1e30f;
    s_red[tid] = uw;
    __syncthreads();
    for (int s = 64; s > 0; s >>= 1) {
        if (tid < s) s_red[tid] = fmaxf(s_red[tid], s_red[tid + s]);
        __syncthreads();
    }
    const float mx = s_red[0];
    __syncthreads();
    float e = (tid < m) ? expf(uw - mx) : 0.0f;

    s_scan[tid] = e;
    __syncthreads();
    #pragma unroll
    for (int off = 1; off < 128; off <<= 1) {
        float v = (tid >= off) ? s_scan[tid - off] : 0.0f;
        __syncthreads();
        s_scan[tid] += v;
        __syncthreads();
    }
    const float S = s_scan[m - 1];
    const float invS = 1.0f / S;
    const float w_i = e * invS;
    if (tid < m) widths[tid] = w_i;
    if (tid == 0) locs[0] = 0.0f;
    if (tid < m) locs[tid + 1] = (tid == m - 1) ? 1.0f : s_scan[tid] * invS;
    __syncthreads();

    // ---- heights ----
    float uh = (tid < n) ? ph[tid] : 0.0f;
    float eh = (tid < n) ? expf(uh) : 0.0f;
    s_h[tid] = eh;
    if (tid == 0) s_h[128] = 0.0f;
    __syncthreads();
    float term = (tid < m) ? 0.5f * (s_h[tid] + s_h[tid + 1]) * w_i : 0.0f;
    s_red[tid] = term;
    __syncthreads();
    for (int s = 64; s > 0; s >>= 1) {
        if (tid < s) s_red[tid] += s_red[tid + s];
        __syncthreads();
    }
    const float area = s_red[0];
    __syncthreads();
    const float inv_area = 1.0f / area;
    if (tid < n) heights[tid] = eh * inv_area;

    float d = term * inv_area;
    s_scan[tid] = d;
    __syncthreads();
    #pragma unroll
    for (int off = 1; off < 128; off <<= 1) {
        float v = (tid >= off) ? s_scan[tid - off] : 0.0f;
        __syncthreads();
        s_scan[tid] += v;
        __syncthreads();
    }
    if (tid == 0) lcdf[0] = 0.0f;
    if (tid < m) lcdf[tid + 1] = (tid == m - 1) ? 1.0f : s_scan[tid];
}

// ---------------------------------------------------------------------------
// Kernel 2: per-tile LDS histogram (no global atomics).
// ---------------------------------------------------------------------------
__global__ void blockhist(const int* __restrict__ gix, int N, int G) {
    __shared__ int h[N_GENES_MAX];
    const int b = blockIdx.x;
    const int tid = threadIdx.x;
    for (int g = tid; g < G; g += blockDim.x) h[g] = 0;
    __syncthreads();

    const int base = b * TILE;
    const int n4 = TILE / 4;
    const int4* gix4 = (const int4*)gix + (base >> 2);
    for (int k = tid; k < n4; k += blockDim.x) {
        const int gi = base + 4 * k;
        if (gi + 3 < N) {
            const int4 v = gix4[k];
            atomicAdd(&h[v.x], 1);
            atomicAdd(&h[v.y], 1);
            atomicAdd(&h[v.z], 1);
            atomicAdd(&h[v.w], 1);
        } else {
            for (int c = 0; c < 4; ++c)
                if (gi + c < N) atomicAdd(&h[gix[gi + c]], 1);
        }
    }
    __syncthreads();
    for (int g = tid; g < G; g += blockDim.x) g_counts[(size_t)b * G + g] = h[g];
}

// ---------------------------------------------------------------------------
// Kernel 3: per-(chunk,gene) partial sums. grid = (ceil(G/256), NCH).
// ---------------------------------------------------------------------------
__global__ void partial_sums(int G, int NB, int CHUNK) {
    const int g = blockIdx.x * blockDim.x + threadIdx.x;
    const int c = blockIdx.y;
    if (g >= G) return;
    const int b0 = c * CHUNK;
    const int b1 = min(b0 + CHUNK, NB);
    int s = 0;
    for (int b = b0; b < b1; ++b) s += g_counts[(size_t)b * G + g];
    g_part[(size_t)c * G + g] = s;
}

// ---------------------------------------------------------------------------
// Kernel 4: gene totals from partials + exclusive scan -> offs[G+1]. 1 block.
// ---------------------------------------------------------------------------
__global__ void scan_genes(int* __restrict__ offs, int G, int N) {
    __shared__ int s_part[1024];
    const int tid = threadIdx.x;
    const int CH = (G + 1023) / 1024;  // <=8
    int local[8];
    int sum = 0;
    for (int k = 0; k < CH; ++k) {
        const int idx = tid * CH + k;
        int v = 0;
        if (idx < G)
            for (int c = 0; c < NCH; ++c) v += g_part[(size_t)c * G + idx];
        local[k] = sum;
        sum += v;
    }
    s_part[tid] = sum;
    __syncthreads();
    for (int off = 1; off < 1024; off <<= 1) {
        int v = (tid >= off) ? s_part[tid - off] : 0;
        __syncthreads();
        s_part[tid] += v;
        __syncthreads();
    }
    const int prev = (tid == 0) ? 0 : s_part[tid - 1];
    for (int k = 0; k < CH; ++k) {
        const int idx = tid * CH + k;
        if (idx < G) offs[idx] = prev + local[k];
    }
    if (tid == 0) offs[G] = N;
}

// ---------------------------------------------------------------------------
// Kernel 5: per-gene scan over chunk partials -> chunkoff. grid = ceil(G/256).
// ---------------------------------------------------------------------------
__global__ void scan_chunks(const int* __restrict__ offs, int G) {
    const int g = blockIdx.x * blockDim.x + threadIdx.x;
    if (g >= G) return;
    int run = offs[g];
    for (int c = 0; c < NCH; ++c) {
        const size_t idx = (size_t)c * G + g;
        g_chunkoff[idx] = run;
        run += g_part[idx];
    }
}

// ---------------------------------------------------------------------------
// Kernel 6: per-(tile,gene) start offsets within chunk. grid = (ceil(G/256), NCH).
// ---------------------------------------------------------------------------
__global__ void tile_offsets(int G, int NB, int CHUNK) {
    const int g = blockIdx.x * blockDim.x + threadIdx.x;
    const int c = blockIdx.y;
    if (g >= G) return;
    const int b0 = c * CHUNK;
    const int b1 = min(b0 + CHUNK, NB);
    int run = g_chunkoff[(size_t)c * G + g];
    for (int b = b0; b < b1; ++b) {
        const size_t idx = (size_t)b * G + g;
        g_offsm[idx] = run;
        run += g_counts[idx];
    }
}

// ---------------------------------------------------------------------------
// Kernel 7: scatter with LDS cursors (no global atomics).
// ---------------------------------------------------------------------------
__global__ void scatter2(const float* __restrict__ x, const int* __restrict__ gix,
                         int N, int G) {
    __shared__ int cur[N_GENES_MAX];
    const int b = blockIdx.x;
    const int tid = threadIdx.x;
    for (int g = tid; g < G; g += blockDim.x) cur[g] = g_offsm[(size_t)b * G + g];
    __syncthreads();

    const int base = b * TILE;
    const int n4 = TILE / 4;
    const int4*   gix4 = (const int4*)gix + (base >> 2);
    const float4* x4p  = (const float4*)x + (base >> 2);
    int4* rank4 = (int4*)g_rank + (base >> 2);
    for (int k = tid; k < n4; k += blockDim.x) {
        const int gi = base + 4 * k;
        if (gi + 3 < N) {
            const int4   g4 = gix4[k];
            const float4 v4 = x4p[k];
            const int p0 = atomicAdd(&cur[g4.x], 1);
            const int p1 = atomicAdd(&cur[g4.y], 1);
            const int p2 = atomicAdd(&cur[g4.z], 1);
            const int p3 = atomicAdd(&cur[g4.w], 1);
            g_sx[p0] = v4.x;
            g_sx[p1] = v4.y;
            g_sx[p2] = v4.z;
            g_sx[p3] = v4.w;
            rank4[k] = make_int4(p0, p1, p2, p3);
        } else {
            for (int c = 0; c < 4; ++c) {
                if (gi + c < N) {
                    const int pos = atomicAdd(&cur[gix[gi + c]], 1);
                    g_sx[pos] = x[gi + c];
                    g_rank[gi + c] = pos;
                }
            }
        }
    }
}

// ---------------------------------------------------------------------------
// Kernel 8: per-gene evaluation with LDS-staged table; coalesced output.
// ---------------------------------------------------------------------------
template <int K>
__device__ __forceinline__ void spline_step_lds(const float* __restrict__ tab,
                                                float& x, float& lad) {
    const float* locs    = tab;
    const float* heights = tab + K;
    const float* lcdf    = tab + 2 * K;
    const float* widths  = tab + 3 * K;

    // Near-uniform bins: guess + local scan. Result equals
    // clip(searchsorted(locs, x, 'right') - 1, 0, K-2).
    int b = (int)(x * (float)(K - 1));
    b = (b < 0) ? 0 : ((b > K - 2) ? K - 2 : b);
    while (b > 0 && locs[b] > x) --b;
    while (b < K - 2 && locs[b + 1] <= x) ++b;

    const float bl = locs[b];
    const float w  = widths[b];
    const float lh = heights[b];
    const float rh = heights[b + 1];
    const float lc = lcdf[b];
    const float alpha = (x - bl) / w;
    float out = (0.5f * (rh - lh) * w) * alpha * alpha + (lh * w) * alpha + lc;
    out = fminf(fmaxf(out, 0.0f), 1.0f);
    lad += __logf(alpha * (rh - lh) + lh);
    x = out;
}

__global__ void spline_eval_sorted(const int* __restrict__ offs) {
    const int g = blockIdx.x;
    __shared__ float s_tab[TABLE_STRIDE];
    const float* tab = g_tables + (size_t)g * TABLE_STRIDE;
    for (int i = threadIdx.x; i < TABLE_STRIDE; i += blockDim.x) s_tab[i] = tab[i];
    __syncthreads();

    const int start = offs[g];
    const int end   = offs[g + 1];
    for (int j = start + threadIdx.x; j < end; j += blockDim.x) {
        float x = g_sx[j];
        float lad = 0.0f;
        spline_step_lds<128>(s_tab, x, lad);
        spline_step_lds<64>(s_tab + 512, x, lad);
        spline_step_lds<32>(s_tab + 768, x, lad);
        g_res[j] = make_float2(x, lad);   // coalesced
    }
}

// ---------------------------------------------------------------------------
// Kernel 9: unpermute — one random 8B gather per element, coalesced writes.
// ---------------------------------------------------------------------------
__global__ void unpermute(float* __restrict__ out, int N) {
    const int i = blockIdx.x * blockDim.x + threadIdx.x;
    if (i >= N) return;
    const int r = g_rank[i];
    const float2 v = g_res[r];
    out[i] = v.x;
    out[N + i] = v.y;
}

// ---------------------------------------------------------------------------
extern "C" void kernel_launch(void* const* d_in, const int* in_sizes, int n_in,
                              void* d_out, int out_size, void* d_ws, size_t ws_size,
                              hipStream_t stream) {
    const float* x      = (const float*)d_in[0];
    const int*   gix    = (const int*)d_in[1];
    const float* params = (const float*)d_in[2];
    float* out = (float*)d_out;

    const int N = in_sizes[0];
    const int G = in_sizes[2] / PARAMS_PER_GENE;
    const int NB = (N + TILE - 1) / TILE;
    const int CHUNK = (NB + NCH - 1) / NCH;

    int* offs = (int*)d_ws;             // [G+1]

    build_tables<<<dim3(G, 3), 128, 0, stream>>>(params);

    const int block = 256;
    const int gblocks = (G + block - 1) / block;
    blockhist<<<NB, block, 0, stream>>>(gix, N, G);
    partial_sums<<<dim3(gblocks, NCH), block, 0, stream>>>(G, NB, CHUNK);
    scan_genes<<<1, 1024, 0, stream>>>(offs, G, N);
    scan_chunks<<<gblocks, block, 0, stream>>>(offs, G);
    tile_offsets<<<dim3(gblocks, NCH), block, 0, stream>>>(G, NB, CHUNK);
    scatter2<<<NB, block, 0, stream>>>(x, gix, N, G);
    spline_eval_sorted<<<G, block, 0, stream>>>(offs);
    unpermute<<<(N + block - 1) / block, block, 0, stream>>>(out, N);
}

// Round 6
// 212.212 us; speedup vs baseline: 5.3330x; 1.4249x over previous
//
#include <hip/hip_runtime.h>
#include <hip/hip_bf16.h>
#include <hip/hip_fp16.h>

// Problem constants (fixed by the reference)
#define N_GENES_MAX 5000
#define PARAMS_PER_GENE 445

// Packed knot: {loc f32 (bits in .x), h f16 (low 16 of .y), cdf f16 (high 16)}.
// Per gene: stage0 128 knots @ off 0, stage1 64 @ 128, stage2 32 @ 192 -> 224.
#define KNOTS_PER_GENE 224

// Persistent table buffer (fully rewritten every launch — graph-capture safe).
__device__ uint2 g_knots[(size_t)N_GENES_MAX * KNOTS_PER_GENE];

static __device__ __forceinline__ unsigned short f2h(float f) {
    union { __half h; unsigned short u; } c;
    c.h = __float2half_rn(f);
    return c.u;
}
static __device__ __forceinline__ float h2f(unsigned short u) {
    union { unsigned short u; __half h; } c;
    c.u = u;
    return __half2float(c.h);
}

// ---------------------------------------------------------------------------
// Kernel 1: build packed per-gene knot tables. grid=(G,3), block=128.
// Knot i of a stage = (locs[i], heights[i], left_cdf[i]).
// ---------------------------------------------------------------------------
__global__ void build_knots(const float* __restrict__ params) {
    const int g = blockIdx.x;
    const int t = blockIdx.y;
    const int ns[3]   = {128, 64, 32};
    const int poff[3] = {0, 255, 382};   // heights start within gene's 445 params
    const int koff[3] = {0, 128, 192};   // knot offset within gene's 224 knots

    const int n = ns[t];
    const int m = n - 1;
    const float* ph = params + (size_t)g * PARAMS_PER_GENE + poff[t];
    const float* pw = ph + n;

    __shared__ float s_scan[128];
    __shared__ float s_h[129];
    __shared__ float s_red[128];
    __shared__ float s_loc[128];
    __shared__ float s_cdf[128];

    const int tid = threadIdx.x;

    // ---- softmax over widths ----
    float uw = (tid < m) ? pw[tid] : -1e30f;
    s_red[tid] = uw;
    __syncthreads();
    for (int s = 64; s > 0; s >>= 1) {
        if (tid < s) s_red[tid] = fmaxf(s_red[tid], s_red[tid + s]);
        __syncthreads();
    }
    const float mx = s_red[0];
    __syncthreads();
    float e = (tid < m) ? expf(uw - mx) : 0.0f;

    // inclusive scan of e
    s_scan[tid] = e;
    __syncthreads();
    #pragma unroll
    for (int off = 1; off < 128; off <<= 1) {
        float v = (tid >= off) ? s_scan[tid - off] : 0.0f;
        __syncthreads();
        s_scan[tid] += v;
        __syncthreads();
    }
    const float S = s_scan[m - 1];
    const float invS = 1.0f / S;
    const float w_i = e * invS;   // widths[tid], valid tid < m
    if (tid == 0) s_loc[0] = 0.0f;
    if (tid < m) s_loc[tid + 1] = (tid == m - 1) ? 1.0f : s_scan[tid] * invS;
    __syncthreads();

    // ---- heights ----
    float uh = (tid < n) ? ph[tid] : 0.0f;
    float eh = (tid < n) ? expf(uh) : 0.0f;
    s_h[tid] = eh;
    if (tid == 0) s_h[128] = 0.0f;
    __syncthreads();
    float term = (tid < m) ? 0.5f * (s_h[tid] + s_h[tid + 1]) * w_i : 0.0f;
    s_red[tid] = term;
    __syncthreads();
    for (int s = 64; s > 0; s >>= 1) {
        if (tid < s) s_red[tid] += s_red[tid + s];
        __syncthreads();
    }
    const float area = s_red[0];
    __syncthreads();
    const float inv_area = 1.0f / area;
    const float hgt = eh * inv_area;   // heights[tid], valid tid < n

    // ---- left CDF: inclusive scan of 0.5*(h[i]+h[i+1])*w[i] ----
    float d = term * inv_area;
    s_scan[tid] = d;
    __syncthreads();
    #pragma unroll
    for (int off = 1; off < 128; off <<= 1) {
        float v = (tid >= off) ? s_scan[tid - off] : 0.0f;
        __syncthreads();
        s_scan[tid] += v;
        __syncthreads();
    }
    if (tid == 0) s_cdf[0] = 0.0f;
    if (tid < m) s_cdf[tid + 1] = (tid == m - 1) ? 1.0f : s_scan[tid];
    __syncthreads();

    // ---- pack & store ----
    if (tid < n) {
        uint2 kt;
        kt.x = __float_as_uint(s_loc[tid]);
        kt.y = ((unsigned)f2h(s_cdf[tid]) << 16) | (unsigned)f2h(hgt);
        g_knots[(size_t)g * KNOTS_PER_GENE + koff[t] + tid] = kt;
    }
}

// ---------------------------------------------------------------------------
// Kernel 2: per-element evaluation — direct gather of 2 packed knots/stage.
// ---------------------------------------------------------------------------
template <int K>
__device__ __forceinline__ void spline_stage(const uint2* __restrict__ kn,
                                             float& x, float& lad) {
    // Near-uniform bins: guess + local walk. Converges to
    // clip(searchsorted(locs, x, 'right') - 1, 0, K-2).
    int b = (int)(x * (float)(K - 1));
    b = (b < 0) ? 0 : ((b > K - 2) ? K - 2 : b);
    uint2 k0 = kn[b];
    uint2 k1 = kn[b + 1];
    float l0 = __uint_as_float(k0.x);
    float l1 = __uint_as_float(k1.x);
    while (b > 0 && l0 > x) {
        --b;
        k1 = k0; l1 = l0;
        k0 = kn[b]; l0 = __uint_as_float(k0.x);
    }
    while (b < K - 2 && l1 <= x) {
        ++b;
        k0 = k1; l0 = l1;
        k1 = kn[b + 1]; l1 = __uint_as_float(k1.x);
    }
    const float lh = h2f((unsigned short)(k0.y & 0xffffu));
    const float lc = h2f((unsigned short)(k0.y >> 16));
    const float rh = h2f((unsigned short)(k1.y & 0xffffu));
    const float w  = l1 - l0;
    const float alpha = (x - l0) / w;
    float o = (0.5f * (rh - lh) * w) * alpha * alpha + (lh * w) * alpha + lc;
    o = fminf(fmaxf(o, 0.0f), 1.0f);
    lad += __logf(alpha * (rh - lh) + lh);
    x = o;
}

__global__ void spline_eval_gather(const float* __restrict__ x_in,
                                   const int* __restrict__ gix,
                                   float* __restrict__ out, int N) {
    const int i = blockIdx.x * blockDim.x + threadIdx.x;
    if (i >= N) return;
    float x = x_in[i];
    const uint2* tab = g_knots + (size_t)gix[i] * KNOTS_PER_GENE;
    float lad = 0.0f;
    spline_stage<128>(tab, x, lad);
    spline_stage<64>(tab + 128, x, lad);
    spline_stage<32>(tab + 192, x, lad);
    out[i] = x;
    out[N + i] = lad;
}

// ---------------------------------------------------------------------------
extern "C" void kernel_launch(void* const* d_in, const int* in_sizes, int n_in,
                              void* d_out, int out_size, void* d_ws, size_t ws_size,
                              hipStream_t stream) {
    const float* x      = (const float*)d_in[0];
    const int*   gix    = (const int*)d_in[1];
    const float* params = (const float*)d_in[2];
    float* out = (float*)d_out;

    const int N = in_sizes[0];
    const int G = in_sizes[2] / PARAMS_PER_GENE;

    build_knots<<<dim3(G, 3), 128, 0, stream>>>(params);

    const int block = 256;
    spline_eval_gather<<<(N + block - 1) / block, block, 0, stream>>>(x, gix, out, N);
}